// Round 9
// baseline (212.171 us; speedup 1.0000x reference)
//
#include <hip/hip_runtime.h>

// Problem constants (match reference)
#define V_ 100000
#define D_ 256
#define M_ 4096
#define C_ 4096
#define L_ 32
#define ROWS_MEMS (M_ + 1)          // 4097 rows in mems_enc (mems + xs_emb)
#define NTASK (1 + M_ + 1 + C_)     // 8194 encode row-tasks
#define NV4 ((V_ * D_) / 4)         // 6.4M float4s in lt

__device__ __forceinline__ float wave_allreduce_sum(float v) {
    #pragma unroll
    for (int off = 32; off >= 1; off >>= 1) v += __shfl_xor(v, off, 64);
    return v;
}

__device__ __forceinline__ unsigned short f2bf_rne(float f) {
    unsigned int u = __float_as_uint(f);
    u += 0x7FFFu + ((u >> 16) & 1u);     // round-to-nearest-even
    return (unsigned short)(u >> 16);
}

// ---------------------------------------------------------------------------
// K0: stream-convert lt (fp32, 102 MB) -> bf16 table (51 MB) in ws.
// ---------------------------------------------------------------------------
__global__ __launch_bounds__(256) void convert_lt(
    const float4* __restrict__ lt4, ushort4* __restrict__ bt4)
{
    const int i = blockIdx.x * 256 + threadIdx.x;
    if (i >= NV4) return;
    const float4 v = lt4[i];
    ushort4 o;
    o.x = f2bf_rne(v.x); o.y = f2bf_rne(v.y);
    o.z = f2bf_rne(v.z); o.w = f2bf_rne(v.w);
    bt4[i] = o;
}

// ---------------------------------------------------------------------------
// K1: fused encode + attention + weighted accumulation.
// INSTRUCTION-COUNT test: bf16 rows are 512 B, so one 16 B/lane wave load
// covers TWO token rows (lanes 0..31 = even token, lanes 32..63 = odd token).
// 16 gather instructions per row instead of 32 — the first variant that
// actually halves the vmem instruction count.
// Each lane accumulates 8 dims at dlo=(lane&31)*8 for its parity; a single
// shfl_xor(32) folds even+odd partials so every lane holds the full row
// (duplicated across halves — reductions scaled by 0.5, writes split so each
// dim is written exactly once).
// ---------------------------------------------------------------------------
__global__ __launch_bounds__(256) void encode_fused(
    const int* __restrict__ xs, const int* __restrict__ mems,
    const int* __restrict__ ys, const int* __restrict__ cands,
    const unsigned short* __restrict__ bt,   // bf16 table [V_, D_]
    const float* __restrict__ freqs,
    float* __restrict__ lhs_raw,   // [256], zeroed: sum_i e_i * row_i
    float* __restrict__ gsum,      // [1],  zeroed: sum_i e_i
    float* __restrict__ out_ys)    // d_out second half: [4097, 256]
{
    __shared__ float s_xf[D_];     // xs embedding
    __shared__ float s_lred[D_];   // block partial of sum e*row
    __shared__ float s_an2, s_ered;

    const int wave = threadIdx.x >> 6;
    const int lane = threadIdx.x & 63;
    const int sub  = lane >> 5;            // 0 = even-token half, 1 = odd
    const int dlo  = (lane & 31) * 8;      // my 8 dims
    const int rt = blockIdx.x * 4 + wave;
    const bool valid = (rt < NTASK);
    const bool batt = (blockIdx.x <= M_ / 4);   // blocks 0..1024 have att rows

    s_lred[threadIdx.x] = 0.f;
    if (threadIdx.x == 0) s_ered = 0.f;

    // ---- wave 0 of att blocks: xs embedding via the same packed gather
    if (batt && wave == 0) {
        int tokx = 0; float wx = 0.f;
        if (lane < L_) { tokx = xs[lane]; wx = freqs[tokx]; }
        const float sx2 = wave_allreduce_sum(wx * wx);
        const float wnx = wx / sqrtf(sx2);
        float xa[8];
        #pragma unroll
        for (int j = 0; j < 8; ++j) xa[j] = 0.f;
        #pragma unroll
        for (int l = 0; l < L_ / 2; ++l) {
            const int   idx = 2 * l + sub;
            const int   t  = __shfl(tokx, idx, 64);
            const float wl = __shfl(wnx,  idx, 64);
            const uint4 p = *reinterpret_cast<const uint4*>(bt + (size_t)t * D_ + dlo);
            xa[0] += wl * __uint_as_float(p.x << 16);
            xa[1] += wl * __uint_as_float(p.x & 0xFFFF0000u);
            xa[2] += wl * __uint_as_float(p.y << 16);
            xa[3] += wl * __uint_as_float(p.y & 0xFFFF0000u);
            xa[4] += wl * __uint_as_float(p.z << 16);
            xa[5] += wl * __uint_as_float(p.z & 0xFFFF0000u);
            xa[6] += wl * __uint_as_float(p.w << 16);
            xa[7] += wl * __uint_as_float(p.w & 0xFFFF0000u);
        }
        #pragma unroll
        for (int j = 0; j < 8; ++j) xa[j] += __shfl_xor(xa[j], 32, 64);
        // each dim written exactly once: sub=0 writes dlo..+4, sub=1 dlo+4..+8
        #pragma unroll
        for (int j = 0; j < 4; ++j) s_xf[dlo + sub * 4 + j] = xa[sub * 4 + j];
        float pq = 0.f;
        #pragma unroll
        for (int j = 0; j < 8; ++j) pq += xa[j] * xa[j];
        const float an2 = wave_allreduce_sum(pq) * 0.5f;   // row duplicated 2x
        if (lane == 0) s_an2 = an2;
    }
    __syncthreads();

    // ---- resolve row task (round-4 mapping)
    const int* tok_ptr = cands; float* dst = nullptr; int ai = -1;
    if (valid) {
        if (rt == 0)           { tok_ptr = xs; ai = M_; }
        else if (rt <= M_)     { tok_ptr = mems + (size_t)(rt - 1) * L_; ai = rt - 1; }
        else if (rt == M_ + 1) { tok_ptr = ys; dst = out_ys; }
        else {
            const int c = rt - (M_ + 2);
            tok_ptr = cands + (size_t)c * L_;
            dst = out_ys + (size_t)(c + 1) * D_;
        }
    }

    // tokens + weights in lanes 0..31
    int tok = 0; float w = 0.f;
    if (valid && lane < L_) { tok = tok_ptr[lane]; w = freqs[tok]; }
    const float s2 = wave_allreduce_sum(w * w);
    const float wn = w / sqrtf(s2);        // junk for invalid waves; unused

    // ---- packed gather: 16 instrs/row, each covering 2 token rows
    float acc[8];
    #pragma unroll
    for (int j = 0; j < 8; ++j) acc[j] = 0.f;
    if (valid) {
        #pragma unroll
        for (int l = 0; l < L_ / 2; ++l) {
            const int   idx = 2 * l + sub;
            const int   t  = __shfl(tok, idx, 64);
            const float wl = __shfl(wn,  idx, 64);
            const uint4 p = *reinterpret_cast<const uint4*>(bt + (size_t)t * D_ + dlo);
            acc[0] += wl * __uint_as_float(p.x << 16);
            acc[1] += wl * __uint_as_float(p.x & 0xFFFF0000u);
            acc[2] += wl * __uint_as_float(p.y << 16);
            acc[3] += wl * __uint_as_float(p.y & 0xFFFF0000u);
            acc[4] += wl * __uint_as_float(p.z << 16);
            acc[5] += wl * __uint_as_float(p.z & 0xFFFF0000u);
            acc[6] += wl * __uint_as_float(p.w << 16);
            acc[7] += wl * __uint_as_float(p.w & 0xFFFF0000u);
        }
        #pragma unroll
        for (int j = 0; j < 8; ++j) acc[j] += __shfl_xor(acc[j], 32, 64);
        // all lanes now hold the full row: dims dlo..dlo+8 (halves duplicate)

        if (ai >= 0) {
            float pd = 0.f, pq = 0.f;
            #pragma unroll
            for (int j = 0; j < 8; ++j) {
                pd += acc[j] * s_xf[dlo + j];
                pq += acc[j] * acc[j];
            }
            const float d = wave_allreduce_sum(pd) * 0.5f;  // dup-corrected
            const float q = wave_allreduce_sum(pq) * 0.5f;
            const float an = fmaxf(sqrtf(s_an2), 1e-8f);
            const float bn = fmaxf(sqrtf(q),  1e-8f);
            const float e = expf(d / (an * bn));   // cos in [-1,1]: no max-sub
            #pragma unroll
            for (int j = 0; j < 4; ++j)            // each dim exactly once
                atomicAdd(&s_lred[dlo + sub * 4 + j], e * acc[sub * 4 + j]);
            if (lane == 0) atomicAdd(&s_ered, e);
        } else {
            const float4 st = make_float4(acc[sub * 4 + 0], acc[sub * 4 + 1],
                                          acc[sub * 4 + 2], acc[sub * 4 + 3]);
            *reinterpret_cast<float4*>(dst + dlo + sub * 4) = st;
        }
    }

    if (batt) {
        __syncthreads();
        atomicAdd(&lhs_raw[threadIdx.x], s_lred[threadIdx.x]);
        if (threadIdx.x == 0) atomicAdd(gsum, s_ered);
    }
}

// ---------------------------------------------------------------------------
// K2: normalize lhs by the softmax denominator and tile into out_xs rows.
// ---------------------------------------------------------------------------
__global__ __launch_bounds__(256) void finalize_tile(
    const float* __restrict__ lhs_raw, const float* __restrict__ gsum,
    float* __restrict__ out_xs)
{
    const float val = lhs_raw[threadIdx.x] / gsum[0];
    for (int r = blockIdx.x; r < ROWS_MEMS; r += gridDim.x)
        out_xs[(size_t)r * D_ + threadIdx.x] = val;
}

extern "C" void kernel_launch(void* const* d_in, const int* in_sizes, int n_in,
                              void* d_out, int out_size, void* d_ws, size_t ws_size,
                              hipStream_t stream) {
    const int*   xs    = (const int*)d_in[0];
    const int*   mems  = (const int*)d_in[1];
    const int*   ys    = (const int*)d_in[2];
    const int*   cands = (const int*)d_in[3];
    const float* lt    = (const float*)d_in[4];
    const float* freqs = (const float*)d_in[5];

    float* out    = (float*)d_out;
    float* out_xs = out;                                   // [4097, 256]
    float* out_ys = out + (size_t)ROWS_MEMS * D_;          // [4097, 256]

    // ws layout: bf16 table [V_*D_ ushort = 51.2 MB] | lhs_raw[256] | gsum[1]
    unsigned short* bt = (unsigned short*)d_ws;
    float* lhs_raw = (float*)(bt + (size_t)V_ * D_);
    float* gsum    = lhs_raw + D_;

    hipMemsetAsync(lhs_raw, 0, (D_ + 1) * sizeof(float), stream);

    convert_lt<<<(NV4 + 255) / 256, 256, 0, stream>>>(
        (const float4*)lt, (ushort4*)bt);
    encode_fused<<<(NTASK + 3) / 4, 256, 0, stream>>>(xs, mems, ys, cands, bt, freqs,
                                                      lhs_raw, gsum, out_ys);
    finalize_tile<<<1024, 256, 0, stream>>>(lhs_raw, gsum, out_xs);
}